// Round 12
// baseline (231.255 us; speedup 1.0000x reference)
//
#include <hip/hip_runtime.h>
#include <hip/hip_bf16.h>

typedef unsigned short u16;
typedef __attribute__((ext_vector_type(8))) short bf16x8;
typedef __attribute__((ext_vector_type(4))) float f32x4;

#define MFMA(a, b, c) __builtin_amdgcn_mfma_f32_16x16x32_bf16(a, b, c, 0, 0, 0)

__device__ inline u16 f2bf(float f) {
    union { __hip_bfloat16 b; u16 u; } cv;
    cv.b = __float2bfloat16(f);
    return cv.u;
}

__device__ inline f32x4 zero4() {
    f32x4 v; v[0] = 0.f; v[1] = 0.f; v[2] = 0.f; v[3] = 0.f; return v;
}

// async global->LDS, 16B per lane. LDS dest must be wave-uniform base (+lane*16 implicit).
__device__ inline void gl_lds16(const u16* g, u16* l) {
    __builtin_amdgcn_global_load_lds(
        (const __attribute__((address_space(1))) u16*)(g),
        (__attribute__((address_space(3))) u16*)(l), 16, 0, 0);
}

// raw barrier: drains LDS ops only, leaves global_load_lds (vmcnt) in flight
__device__ inline void barrier_nodrain() {
    asm volatile("s_waitcnt lgkmcnt(0)\ns_barrier" ::: "memory");
}

// ---------------- prep: fp32->bf16 conversions + weight transposes + marg zero ----------------
__global__ __launch_bounds__(256) void prep_kernel(const float* __restrict__ qa, const float* __restrict__ kva,
                                                   u16* __restrict__ oq, u16* __restrict__ okv,
                                                   const float* __restrict__ wq, const float* __restrict__ wk,
                                                   const float* __restrict__ wv, const float* __restrict__ wo,
                                                   u16* __restrict__ W3, u16* __restrict__ Wot,
                                                   float* __restrict__ marg) {
    __shared__ float tile[64][65];
    int bid = blockIdx.x, tid = threadIdx.x;
    if (bid >= 9216) {  // zero marg (replaces memset dispatch)
        for (int i = tid; i < 4096; i += 256) marg[i] = 0.f;
        return;
    }
    if (bid < 8192) {
        const float* in = (bid < 4096) ? qa : kva;
        u16* out = (bid < 4096) ? oq : okv;
        int i = (((bid & 4095) * 256) + tid) * 4;
        float4 v = *(const float4*)(in + i);
        u16 o[4] = { f2bf(v.x), f2bf(v.y), f2bf(v.z), f2bf(v.w) };
        *(uint2*)(out + i) = *(const uint2*)o;
        return;
    }
    int v_ = bid - 8192;
    int bx = v_ & 15, by = (v_ >> 4) & 3, h = v_ >> 6;
    const float* src; u16* dst; int R, C, ho, r0, c0;
    if (by == 3) { src = wo; dst = Wot; R = 64; C = 1024; ho = 64; r0 = 0; c0 = bx * 64; }
    else {
        src = (by == 0) ? wq : (by == 1) ? wk : wv;
        dst = W3 + (size_t)by * 1024 * 1024;
        R = 1024; C = 64; ho = 64 * 1024; r0 = bx * 64; c0 = 0;
    }
    const float* s = src + (size_t)h * R * C;
#pragma unroll
    for (int k = 0; k < 16; k++) {
        int idx = tid + k * 256;
        int i = idx >> 6, j = idx & 63;
        tile[i][j] = s[(size_t)(r0 + i) * C + (c0 + j)];
    }
    __syncthreads();
    u16* d = dst + (size_t)h * ho;
#pragma unroll
    for (int k = 0; k < 16; k++) {
        int idx = tid + k * 256;
        int j = idx >> 6, i = idx & 63;
        d[(size_t)(c0 + j) * 1024 + (r0 + i)] = f2bf(tile[i][j]);
    }
}

// Q pre-scale: kscale * log2(e), folded into proj epilogue so attn uses exp2 directly.
#define QSC 0.18033688011112042f

// ---------------- fused QKV projection GEMM: KV-fused blocks + XCD-pinned B columns (R11) ----------------
__global__ __launch_bounds__(256, 2) void proj_kernel(const u16* __restrict__ Xq, const u16* __restrict__ Xkv,
                                                      const u16* __restrict__ W3,
                                                      u16* __restrict__ Qp, u16* __restrict__ Kp,
                                                      u16* __restrict__ Vt) {
    __shared__ __align__(16) union ShM {
        struct { u16 As[128 * 32]; u16 B0[128 * 32]; u16 B1[128 * 32]; } d;
        u16 Ts[128 * 136];
    } sh;
    int tid = threadIdx.x;
    int bid = blockIdx.x;
    int ny = bid & 15, mblk = bid >> 4;
    int m0 = mblk * 128, n0 = (ny & 7) * 128;
    bool isQ = (ny < 8);
    const u16* Ap  = isQ ? Xq : Xkv;
    const u16* BtK = W3 + (size_t)(isQ ? 0 : 1) * 1024 * 1024 + (size_t)n0 * 1024;
    const u16* BtV = W3 + (size_t)2 * 1024 * 1024 + (size_t)n0 * 1024;
    int w = tid >> 6, lane = tid & 63, quad = lane >> 4, c = lane & 15;
    int mw = (w & 1) * 64, nw = (w >> 1) * 64;
    f32x4 acc0[4][4], acc1[4][4];
#pragma unroll
    for (int i = 0; i < 4; i++)
#pragma unroll
        for (int j = 0; j < 4; j++) { acc0[i][j] = zero4(); acc1[i][j] = zero4(); }

    for (int k0 = 0; k0 < 1024; k0 += 32) {
        __syncthreads();
#pragma unroll
        for (int s = 0; s < 2; s++) {
            int ch = s * 256 + w * 64 + lane;
            int r = ch >> 2, cc = (ch & 3) * 8;
            gl_lds16(&Ap[(size_t)(m0 + r) * 1024 + k0 + cc],  &sh.d.As[(s * 256 + w * 64) * 8]);
            gl_lds16(&BtK[(size_t)r * 1024 + k0 + cc],        &sh.d.B0[(s * 256 + w * 64) * 8]);
            if (!isQ) gl_lds16(&BtV[(size_t)r * 1024 + k0 + cc], &sh.d.B1[(s * 256 + w * 64) * 8]);
        }
        asm volatile("s_waitcnt vmcnt(0)" ::: "memory");
        __syncthreads();
        bf16x8 af[4], bf0[4];
#pragma unroll
        for (int i = 0; i < 4; i++) af[i] = *(const bf16x8*)&sh.d.As[(mw + i * 16 + c) * 32 + quad * 8];
#pragma unroll
        for (int j = 0; j < 4; j++) bf0[j] = *(const bf16x8*)&sh.d.B0[(nw + j * 16 + c) * 32 + quad * 8];
#pragma unroll
        for (int i = 0; i < 4; i++)
#pragma unroll
            for (int j = 0; j < 4; j++) acc0[i][j] = MFMA(af[i], bf0[j], acc0[i][j]);
        if (!isQ) {
            bf16x8 bf1[4];
#pragma unroll
            for (int j = 0; j < 4; j++) bf1[j] = *(const bf16x8*)&sh.d.B1[(nw + j * 16 + c) * 32 + quad * 8];
#pragma unroll
            for (int i = 0; i < 4; i++)
#pragma unroll
                for (int j = 0; j < 4; j++) acc1[i][j] = MFMA(af[i], bf1[j], acc1[i][j]);
        }
    }
    if (isQ) {
#pragma unroll
        for (int i = 0; i < 4; i++)
#pragma unroll
            for (int r = 0; r < 4; r++) {
                int row = m0 + mw + i * 16 + quad * 4 + r;
#pragma unroll
                for (int j = 0; j < 4; j++)
                    Qp[(size_t)row * 1024 + n0 + nw + j * 16 + c] = f2bf(acc0[i][j][r] * QSC);
            }
    } else {
#pragma unroll
        for (int i = 0; i < 4; i++)
#pragma unroll
            for (int r = 0; r < 4; r++) {
                int row = m0 + mw + i * 16 + quad * 4 + r;
#pragma unroll
                for (int j = 0; j < 4; j++)
                    Kp[(size_t)row * 1024 + n0 + nw + j * 16 + c] = f2bf(acc0[i][j][r]);
            }
        __syncthreads();  // all frag reads done before Ts overwrites As/B0/B1
#pragma unroll
        for (int i = 0; i < 4; i++)
#pragma unroll
            for (int r = 0; r < 4; r++) {
                int rowL = mw + i * 16 + quad * 4 + r;
#pragma unroll
                for (int j = 0; j < 4; j++)
                    sh.Ts[(nw + j * 16 + c) * 136 + rowL] = f2bf(acc1[i][j][r]);
            }
        __syncthreads();
        int bb = m0 >> 10, tbase = m0 & 1023;
#pragma unroll
        for (int it = 0; it < 8; it++) {
            int linear = tid + it * 256;
            int colL = linear >> 4, r0 = (linear & 15) * 8;
            int colG = n0 + colL;
            bf16x8 v = *(const bf16x8*)&sh.Ts[colL * 136 + r0];
            *(bf16x8*)&Vt[(((size_t)(bb * 16 + (colG >> 6)) * 64) + (colG & 63)) * 1024 + tbase + r0] = v;
        }
    }
}

// ---------------- output projection GEMM (XCD-pinned) + entropy tail blocks (R11) ----------------
__global__ __launch_bounds__(256) void gemmo_kernel(const u16* __restrict__ A, const u16* __restrict__ Bt,
                                                    float* __restrict__ Cf, const float* __restrict__ qmask,
                                                    const float* __restrict__ marg, float* __restrict__ entr) {
    __shared__ __align__(16) u16 As[128 * 32];
    __shared__ __align__(16) u16 Bs[128 * 32];
    __shared__ float red[256];
    int tid = threadIdx.x;
    int bid = blockIdx.x;
    if (bid >= 256) {  // entropy: marg (B,1024) -> scaled_entr
        int b = bid - 256;
        float s = 0.f;
        for (int t = tid; t < 1024; t += 256) s += marg[b * 1024 + t];
        red[tid] = s; __syncthreads();
        for (int k = 128; k > 0; k >>= 1) { if (tid < k) red[tid] += red[tid + k]; __syncthreads(); }
        float tot = red[0];
        __syncthreads();
        float e = 0.f;
        for (int t = tid; t < 1024; t += 256) {
            float p = marg[b * 1024 + t] / tot;
            if (p > 0.f) e -= p * log2f(p);
        }
        red[tid] = e; __syncthreads();
        for (int k = 128; k > 0; k >>= 1) { if (tid < k) red[tid] += red[tid + k]; __syncthreads(); }
        if (tid == 0) entr[b] = red[0] * 0.1f;  // / log2(c=1024)
        return;
    }
    int m0 = (bid >> 3) * 128, n0 = (bid & 7) * 128;
    int w = tid >> 6, lane = tid & 63, quad = lane >> 4, c = lane & 15;
    int mw = (w & 1) * 64, nw = (w >> 1) * 64;
    f32x4 acc[4][4];
#pragma unroll
    for (int i = 0; i < 4; i++)
#pragma unroll
        for (int j = 0; j < 4; j++) acc[i][j] = zero4();

    for (int k0 = 0; k0 < 1024; k0 += 32) {
        __syncthreads();
#pragma unroll
        for (int s = 0; s < 2; s++) {
            int ch = s * 256 + w * 64 + lane;
            int r = ch >> 2, cc = (ch & 3) * 8;
            gl_lds16(&A[(size_t)(m0 + r) * 1024 + k0 + cc],  &As[(s * 256 + w * 64) * 8]);
            gl_lds16(&Bt[(size_t)(n0 + r) * 1024 + k0 + cc], &Bs[(s * 256 + w * 64) * 8]);
        }
        asm volatile("s_waitcnt vmcnt(0)" ::: "memory");
        __syncthreads();
        bf16x8 af[4], bfr[4];
#pragma unroll
        for (int i = 0; i < 4; i++) af[i] = *(const bf16x8*)&As[(mw + i * 16 + c) * 32 + quad * 8];
#pragma unroll
        for (int j = 0; j < 4; j++) bfr[j] = *(const bf16x8*)&Bs[(nw + j * 16 + c) * 32 + quad * 8];
#pragma unroll
        for (int i = 0; i < 4; i++)
#pragma unroll
            for (int j = 0; j < 4; j++) acc[i][j] = MFMA(af[i], bfr[j], acc[i][j]);
    }
#pragma unroll
    for (int i = 0; i < 4; i++) {
#pragma unroll
        for (int r = 0; r < 4; r++) {
            int row = m0 + mw + i * 16 + quad * 4 + r;
            float scale = 1.0f - qmask[row];
#pragma unroll
            for (int j = 0; j < 4; j++) {
                int col = n0 + nw + j * 16 + c;
                Cf[(size_t)row * 1024 + col] = acc[i][j][r] * scale;
            }
        }
    }
}

// ---------------- flash attention: single-sweep with fp8 e-cache in registers ----------------
// 1D grid 512, 512 thr, cohort perm {0,7,1,6,2,5,3,4}, pair-balanced (waves 0-3 heavy 15-m,
// waves 4-7 light m). Sweep 1 (normal-S orientation) computes S, e=exp2(s), l, PV — and packs
// e*0.5 into an fp8 register cache ec[16][4] (64 VGPR; full unroll keeps it in regs).
// Phase 2 (NO barriers, NO staging, NO MFMA, NO exp2): unpack ec, *2*wr, 2 shuffles, LDS atomic.
// This deletes the old sweep 2's K re-staging + S recompute + exp2 entirely.
__global__ __launch_bounds__(512) void attn_kernel(const u16* __restrict__ Qp, const u16* __restrict__ Kp,
                                                   const u16* __restrict__ Vt, u16* __restrict__ Pre,
                                                   float* __restrict__ marg) {
    __shared__ __align__(16) u16 Ks[2][64 * 64];
    __shared__ __align__(16) u16 Vs[2][64 * 64];
    __shared__ __align__(16) u16 plds[8][16 * 72];
    float* colbuf = (float*)&Vs[0][0];   // 4KB alias; live only in phase 2
    int tid = threadIdx.x;
    int bid = blockIdx.x;
    int k2 = bid >> 6;
    int m = (k2 & 1) ? (7 - (k2 >> 1)) : (k2 >> 1);  // cohort perm {0,7,1,6,2,5,3,4}
    int g = bid & 63;
    int h = g & 15, b = g >> 4;
    int bx = m;
    int nA = 16 - bx, nB = bx + 1;
    int w = tid >> 6, lane = tid & 63, quad = lane >> 4, c = lane & 15;

    int nq = (w < 4) ? nA : nB;
    int q0 = (w < 4) ? ((15 - bx) * 64 + w * 16) : (bx * 64 + (w - 4) * 16);

    const u16* qrow = Qp + (size_t)(b * 1024 + q0 + c) * 1024 + h * 64;
    bf16x8 aq0 = *(const bf16x8*)(qrow + quad * 8);
    bf16x8 aq1 = *(const bf16x8*)(qrow + 32 + quad * 8);

    const u16* kb = Kp + (size_t)b * 1024 * 1024 + h * 64;
    const u16* vb = Vt + (size_t)(b * 16 + h) * 64 * 1024;
    u16* pl = plds[w];

    int rowS = tid >> 3;
    int lu = (tid & 7) ^ (rowS & 7);
    int sw = c & 7;
    int su0 = (quad ^ sw) * 8;
    int su1 = ((quad ^ 4) ^ sw) * 8;
    u16* ldsK = &Ks[0][0] + w * 512;
    u16* ldsV = &Vs[0][0] + w * 512;

    f32x4 o[4];
#pragma unroll
    for (int i = 0; i < 4; i++) o[i] = zero4();
    float l[4] = {0.f, 0.f, 0.f, 0.f};
    int qg[4];
#pragma unroll
    for (int r = 0; r < 4; r++) qg[r] = q0 + quad * 4 + r;
    unsigned ec[16][4];                  // fp8 e-cache (e*0.5, e4m3): 64 VGPRs

    // ---------------- sweep 1: S -> exp -> P(LDS) + fp8 cache -> PV, row sums ----------------
    gl_lds16(kb + (size_t)rowS * 1024 + lu * 8, ldsK);
    gl_lds16(vb + (size_t)rowS * 1024 + lu * 8, ldsV);
#pragma unroll
    for (int ci = 0; ci < 16; ci++) {
        if (ci < nA) {  // block-uniform guard
            int bf = ci & 1;
            barrier_nodrain();
            if (ci + 1 < nA) {
                gl_lds16(kb + (size_t)((ci + 1) * 64 + rowS) * 1024 + lu * 8, ldsK + (bf ^ 1) * 4096);
                gl_lds16(vb + (size_t)rowS * 1024 + (ci + 1) * 64 + lu * 8,  ldsV + (bf ^ 1) * 4096);
                asm volatile("s_waitcnt vmcnt(2)" ::: "memory");
            } else {
                asm volatile("s_waitcnt vmcnt(0)" ::: "memory");
            }
            asm volatile("s_barrier" ::: "memory");
            if (ci < nq) {
                const u16* Kb = &Ks[bf][0];
                const u16* Vb = &Vs[bf][0];
                f32x4 s[4];
#pragma unroll
                for (int j = 0; j < 4; j++) {
                    const u16* kr = Kb + (j * 16 + c) * 64;
                    s[j] = MFMA(aq0, *(const bf16x8*)(kr + su0), zero4());
                    s[j] = MFMA(aq1, *(const bf16x8*)(kr + su1), s[j]);
                }
                bool diag = (ci == nq - 1);
#pragma unroll
                for (int j = 0; j < 4; j++) {
                    int t = ci * 64 + j * 16 + c;
                    float e[4];
#pragma unroll
                    for (int r = 0; r < 4; r++) {
                        e[r] = (!diag || t <= qg[r]) ? exp2f(s[j][r]) : 0.f;
                        l[r] += e[r];
                        pl[(quad * 4 + r) * 72 + j * 16 + c] = f2bf(e[r]);
                    }
                    int pk = __builtin_amdgcn_cvt_pk_fp8_f32(fminf(e[0] * 0.5f, 448.f),
                                                             fminf(e[1] * 0.5f, 448.f), 0, false);
                    pk = __builtin_amdgcn_cvt_pk_fp8_f32(fminf(e[2] * 0.5f, 448.f),
                                                         fminf(e[3] * 0.5f, 448.f), pk, true);
                    ec[ci][j] = (unsigned)pk;
                }
                asm volatile("s_waitcnt lgkmcnt(0)" ::: "memory");
                bf16x8 ap0 = *(const bf16x8*)&pl[c * 72 + quad * 8];
                bf16x8 ap1 = *(const bf16x8*)&pl[c * 72 + 32 + quad * 8];
#pragma unroll
                for (int vt = 0; vt < 4; vt++) {
                    const u16* vr = Vb + (vt * 16 + c) * 64;
                    o[vt] = MFMA(ap0, *(const bf16x8*)(vr + su0), o[vt]);
                    o[vt] = MFMA(ap1, *(const bf16x8*)(vr + su1), o[vt]);
                }
            }
        }
    }

    float invl[4];
#pragma unroll
    for (int r = 0; r < 4; r++) {
        float lr = l[r];
#pragma unroll
        for (int d = 1; d < 16; d <<= 1) lr += __shfl_xor(lr, d);
        invl[r] = 1.0f / lr;
    }
#pragma unroll
    for (int vt = 0; vt < 4; vt++)
#pragma unroll
        for (int r = 0; r < 4; r++) {
            size_t row = (size_t)(b * 1024 + q0 + quad * 4 + r);
            Pre[row * 1024 + h * 64 + vt * 16 + c] = f2bf(o[vt][r] * invl[r]);
        }

    // ---------------- phase 2: column marginals from register cache (barrier-free) ----------------
    float wr2[4];
#pragma unroll
    for (int r = 0; r < 4; r++) wr2[r] = 2.0f * (float)(qg[r] + 1) * invl[r];  // x2: fp8 stored e*0.5
    __syncthreads();                                  // all Vs reads of sweep 1 done -> colbuf alias safe
    for (int i = tid; i < nA * 64; i += 512) colbuf[i] = 0.f;
    __syncthreads();                                  // colbuf init visible
#pragma unroll
    for (int ci = 0; ci < 16; ci++) {
        if (ci < nq) {
            float a[4];
#pragma unroll
            for (int j = 0; j < 4; j++) {
                int pk = (int)ec[ci][j];
                float v = __builtin_amdgcn_cvt_f32_fp8(pk, 0) * wr2[0]
                        + __builtin_amdgcn_cvt_f32_fp8(pk, 1) * wr2[1]
                        + __builtin_amdgcn_cvt_f32_fp8(pk, 2) * wr2[2]
                        + __builtin_amdgcn_cvt_f32_fp8(pk, 3) * wr2[3];
                v += __shfl_xor(v, 16);
                v += __shfl_xor(v, 32);
                a[j] = v;
            }
            float v = (quad == 0) ? a[0] : (quad == 1) ? a[1] : (quad == 2) ? a[2] : a[3];
            atomicAdd(&colbuf[ci * 64 + lane], v);
        }
    }
    __syncthreads();
    for (int t = tid; t < nA * 64; t += 512) atomicAdd(&marg[b * 1024 + t], colbuf[t]);
}

extern "C" void kernel_launch(void* const* d_in, const int* in_sizes, int n_in,
                              void* d_out, int out_size, void* d_ws, size_t ws_size,
                              hipStream_t stream) {
    const float* qinput  = (const float*)d_in[0];
    const float* kvinput = (const float*)d_in[1];
    const float* qmask   = (const float*)d_in[2];
    const float* wq = (const float*)d_in[5];
    const float* wk = (const float*)d_in[6];
    const float* wv = (const float*)d_in[7];
    const float* wo = (const float*)d_in[8];

    char* ws = (char*)d_ws;
    const size_t MB = 1024 * 1024;
    u16* Xq   = (u16*)(ws + 0);        // 8MB, reused as Pre after Q-proj consumed
    u16* Xkv  = (u16*)(ws + 8 * MB);   // 8MB
    u16* W3   = (u16*)(ws + 16 * MB);  // Wqt|Wkt|Wvt contiguous, 2MB each
    u16* Wot  = (u16*)(ws + 22 * MB);
    u16* Qp   = (u16*)(ws + 24 * MB);  // 8MB (pre-scaled by QSC)
    u16* Kp   = (u16*)(ws + 32 * MB);  // 8MB
    u16* Vt   = (u16*)(ws + 40 * MB);  // 8MB (B,H,V,T)
    float* marg = (float*)(ws + 48 * MB);  // 16KB
    u16* Pre = Xq;
    float* out = (float*)d_out;

    prep_kernel<<<9217, 256, 0, stream>>>(qinput, kvinput, Xq, Xkv, wq, wk, wv, wo, W3, Wot, marg);
    proj_kernel<<<512, 256, 0, stream>>>(Xq, Xkv, W3, Qp, Kp, Vt);

    attn_kernel<<<512, 512, 0, stream>>>(Qp, Kp, Vt, Pre, marg);  // Pre overwrites Xq
    gemmo_kernel<<<260, 256, 0, stream>>>(Pre, Wot, out, qmask, marg, out + (size_t)4 * 1024 * 1024);
}

// Round 13
// 214.376 us; speedup vs baseline: 1.0787x; 1.0787x over previous
//
#include <hip/hip_runtime.h>
#include <hip/hip_bf16.h>

typedef unsigned short u16;
typedef __attribute__((ext_vector_type(8))) short bf16x8;
typedef __attribute__((ext_vector_type(4))) float f32x4;

#define MFMA(a, b, c) __builtin_amdgcn_mfma_f32_16x16x32_bf16(a, b, c, 0, 0, 0)

__device__ inline u16 f2bf(float f) {
    union { __hip_bfloat16 b; u16 u; } cv;
    cv.b = __float2bfloat16(f);
    return cv.u;
}

__device__ inline f32x4 zero4() {
    f32x4 v; v[0] = 0.f; v[1] = 0.f; v[2] = 0.f; v[3] = 0.f; return v;
}

// async global->LDS, 16B per lane. LDS dest must be wave-uniform base (+lane*16 implicit).
__device__ inline void gl_lds16(const u16* g, u16* l) {
    __builtin_amdgcn_global_load_lds(
        (const __attribute__((address_space(1))) u16*)(g),
        (__attribute__((address_space(3))) u16*)(l), 16, 0, 0);
}

// raw barrier: drains LDS ops only, leaves global_load_lds (vmcnt) in flight
__device__ inline void barrier_nodrain() {
    asm volatile("s_waitcnt lgkmcnt(0)\ns_barrier" ::: "memory");
}

// ---------------- prep: fp32->bf16 conversions + weight transposes + marg zero ----------------
__global__ __launch_bounds__(256) void prep_kernel(const float* __restrict__ qa, const float* __restrict__ kva,
                                                   u16* __restrict__ oq, u16* __restrict__ okv,
                                                   const float* __restrict__ wq, const float* __restrict__ wk,
                                                   const float* __restrict__ wv, const float* __restrict__ wo,
                                                   u16* __restrict__ W3, u16* __restrict__ Wot,
                                                   float* __restrict__ marg) {
    __shared__ float tile[64][65];
    int bid = blockIdx.x, tid = threadIdx.x;
    if (bid >= 9216) {  // zero marg (replaces memset dispatch)
        for (int i = tid; i < 4096; i += 256) marg[i] = 0.f;
        return;
    }
    if (bid < 8192) {
        const float* in = (bid < 4096) ? qa : kva;
        u16* out = (bid < 4096) ? oq : okv;
        int i = (((bid & 4095) * 256) + tid) * 4;
        float4 v = *(const float4*)(in + i);
        u16 o[4] = { f2bf(v.x), f2bf(v.y), f2bf(v.z), f2bf(v.w) };
        *(uint2*)(out + i) = *(const uint2*)o;
        return;
    }
    int v_ = bid - 8192;
    int bx = v_ & 15, by = (v_ >> 4) & 3, h = v_ >> 6;
    const float* src; u16* dst; int R, C, ho, r0, c0;
    if (by == 3) { src = wo; dst = Wot; R = 64; C = 1024; ho = 64; r0 = 0; c0 = bx * 64; }
    else {
        src = (by == 0) ? wq : (by == 1) ? wk : wv;
        dst = W3 + (size_t)by * 1024 * 1024;
        R = 1024; C = 64; ho = 64 * 1024; r0 = bx * 64; c0 = 0;
    }
    const float* s = src + (size_t)h * R * C;
#pragma unroll
    for (int k = 0; k < 16; k++) {
        int idx = tid + k * 256;
        int i = idx >> 6, j = idx & 63;
        tile[i][j] = s[(size_t)(r0 + i) * C + (c0 + j)];
    }
    __syncthreads();
    u16* d = dst + (size_t)h * ho;
#pragma unroll
    for (int k = 0; k < 16; k++) {
        int idx = tid + k * 256;
        int j = idx >> 6, i = idx & 63;
        d[(size_t)(c0 + j) * 1024 + (r0 + i)] = f2bf(tile[i][j]);
    }
}

// Q pre-scale: kscale * log2(e), folded into proj epilogue so attn uses exp2 directly.
#define QSC 0.18033688011112042f

// ---------------- fused QKV projection GEMM: KV-fused blocks + XCD-pinned B columns ----------------
__global__ __launch_bounds__(256, 2) void proj_kernel(const u16* __restrict__ Xq, const u16* __restrict__ Xkv,
                                                      const u16* __restrict__ W3,
                                                      u16* __restrict__ Qp, u16* __restrict__ Kp,
                                                      u16* __restrict__ Vt) {
    __shared__ __align__(16) union ShM {
        struct { u16 As[128 * 32]; u16 B0[128 * 32]; u16 B1[128 * 32]; } d;
        u16 Ts[128 * 136];
    } sh;
    int tid = threadIdx.x;
    int bid = blockIdx.x;
    int ny = bid & 15, mblk = bid >> 4;
    int m0 = mblk * 128, n0 = (ny & 7) * 128;
    bool isQ = (ny < 8);
    const u16* Ap  = isQ ? Xq : Xkv;
    const u16* BtK = W3 + (size_t)(isQ ? 0 : 1) * 1024 * 1024 + (size_t)n0 * 1024;
    const u16* BtV = W3 + (size_t)2 * 1024 * 1024 + (size_t)n0 * 1024;
    int w = tid >> 6, lane = tid & 63, quad = lane >> 4, c = lane & 15;
    int mw = (w & 1) * 64, nw = (w >> 1) * 64;
    f32x4 acc0[4][4], acc1[4][4];
#pragma unroll
    for (int i = 0; i < 4; i++)
#pragma unroll
        for (int j = 0; j < 4; j++) { acc0[i][j] = zero4(); acc1[i][j] = zero4(); }

    for (int k0 = 0; k0 < 1024; k0 += 32) {
        __syncthreads();
#pragma unroll
        for (int s = 0; s < 2; s++) {
            int ch = s * 256 + w * 64 + lane;
            int r = ch >> 2, cc = (ch & 3) * 8;
            gl_lds16(&Ap[(size_t)(m0 + r) * 1024 + k0 + cc],  &sh.d.As[(s * 256 + w * 64) * 8]);
            gl_lds16(&BtK[(size_t)r * 1024 + k0 + cc],        &sh.d.B0[(s * 256 + w * 64) * 8]);
            if (!isQ) gl_lds16(&BtV[(size_t)r * 1024 + k0 + cc], &sh.d.B1[(s * 256 + w * 64) * 8]);
        }
        asm volatile("s_waitcnt vmcnt(0)" ::: "memory");
        __syncthreads();
        bf16x8 af[4], bf0[4];
#pragma unroll
        for (int i = 0; i < 4; i++) af[i] = *(const bf16x8*)&sh.d.As[(mw + i * 16 + c) * 32 + quad * 8];
#pragma unroll
        for (int j = 0; j < 4; j++) bf0[j] = *(const bf16x8*)&sh.d.B0[(nw + j * 16 + c) * 32 + quad * 8];
#pragma unroll
        for (int i = 0; i < 4; i++)
#pragma unroll
            for (int j = 0; j < 4; j++) acc0[i][j] = MFMA(af[i], bf0[j], acc0[i][j]);
        if (!isQ) {
            bf16x8 bf1[4];
#pragma unroll
            for (int j = 0; j < 4; j++) bf1[j] = *(const bf16x8*)&sh.d.B1[(nw + j * 16 + c) * 32 + quad * 8];
#pragma unroll
            for (int i = 0; i < 4; i++)
#pragma unroll
                for (int j = 0; j < 4; j++) acc1[i][j] = MFMA(af[i], bf1[j], acc1[i][j]);
        }
    }
    if (isQ) {
#pragma unroll
        for (int i = 0; i < 4; i++)
#pragma unroll
            for (int r = 0; r < 4; r++) {
                int row = m0 + mw + i * 16 + quad * 4 + r;
#pragma unroll
                for (int j = 0; j < 4; j++)
                    Qp[(size_t)row * 1024 + n0 + nw + j * 16 + c] = f2bf(acc0[i][j][r] * QSC);
            }
    } else {
#pragma unroll
        for (int i = 0; i < 4; i++)
#pragma unroll
            for (int r = 0; r < 4; r++) {
                int row = m0 + mw + i * 16 + quad * 4 + r;
#pragma unroll
                for (int j = 0; j < 4; j++)
                    Kp[(size_t)row * 1024 + n0 + nw + j * 16 + c] = f2bf(acc0[i][j][r]);
            }
        __syncthreads();  // all frag reads done before Ts overwrites As/B0/B1
#pragma unroll
        for (int i = 0; i < 4; i++)
#pragma unroll
            for (int r = 0; r < 4; r++) {
                int rowL = mw + i * 16 + quad * 4 + r;
#pragma unroll
                for (int j = 0; j < 4; j++)
                    sh.Ts[(nw + j * 16 + c) * 136 + rowL] = f2bf(acc1[i][j][r]);
            }
        __syncthreads();
        int bb = m0 >> 10, tbase = m0 & 1023;
#pragma unroll
        for (int it = 0; it < 8; it++) {
            int linear = tid + it * 256;
            int colL = linear >> 4, r0 = (linear & 15) * 8;
            int colG = n0 + colL;
            bf16x8 v = *(const bf16x8*)&sh.Ts[colL * 136 + r0];
            *(bf16x8*)&Vt[(((size_t)(bb * 16 + (colG >> 6)) * 64) + (colG & 63)) * 1024 + tbase + r0] = v;
        }
    }
}

// ---------------- output projection GEMM (XCD-pinned) + entropy tail blocks ----------------
__global__ __launch_bounds__(256) void gemmo_kernel(const u16* __restrict__ A, const u16* __restrict__ Bt,
                                                    float* __restrict__ Cf, const float* __restrict__ qmask,
                                                    const float* __restrict__ marg, float* __restrict__ entr) {
    __shared__ __align__(16) u16 As[128 * 32];
    __shared__ __align__(16) u16 Bs[128 * 32];
    __shared__ float red[256];
    int tid = threadIdx.x;
    int bid = blockIdx.x;
    if (bid >= 256) {  // entropy: marg (B,1024) -> scaled_entr
        int b = bid - 256;
        float s = 0.f;
        for (int t = tid; t < 1024; t += 256) s += marg[b * 1024 + t];
        red[tid] = s; __syncthreads();
        for (int k = 128; k > 0; k >>= 1) { if (tid < k) red[tid] += red[tid + k]; __syncthreads(); }
        float tot = red[0];
        __syncthreads();
        float e = 0.f;
        for (int t = tid; t < 1024; t += 256) {
            float p = marg[b * 1024 + t] / tot;
            if (p > 0.f) e -= p * log2f(p);
        }
        red[tid] = e; __syncthreads();
        for (int k = 128; k > 0; k >>= 1) { if (tid < k) red[tid] += red[tid + k]; __syncthreads(); }
        if (tid == 0) entr[b] = red[0] * 0.1f;  // / log2(c=1024)
        return;
    }
    int m0 = (bid >> 3) * 128, n0 = (bid & 7) * 128;
    int w = tid >> 6, lane = tid & 63, quad = lane >> 4, c = lane & 15;
    int mw = (w & 1) * 64, nw = (w >> 1) * 64;
    f32x4 acc[4][4];
#pragma unroll
    for (int i = 0; i < 4; i++)
#pragma unroll
        for (int j = 0; j < 4; j++) acc[i][j] = zero4();

    for (int k0 = 0; k0 < 1024; k0 += 32) {
        __syncthreads();
#pragma unroll
        for (int s = 0; s < 2; s++) {
            int ch = s * 256 + w * 64 + lane;
            int r = ch >> 2, cc = (ch & 3) * 8;
            gl_lds16(&A[(size_t)(m0 + r) * 1024 + k0 + cc],  &As[(s * 256 + w * 64) * 8]);
            gl_lds16(&Bt[(size_t)(n0 + r) * 1024 + k0 + cc], &Bs[(s * 256 + w * 64) * 8]);
        }
        asm volatile("s_waitcnt vmcnt(0)" ::: "memory");
        __syncthreads();
        bf16x8 af[4], bfr[4];
#pragma unroll
        for (int i = 0; i < 4; i++) af[i] = *(const bf16x8*)&As[(mw + i * 16 + c) * 32 + quad * 8];
#pragma unroll
        for (int j = 0; j < 4; j++) bfr[j] = *(const bf16x8*)&Bs[(nw + j * 16 + c) * 32 + quad * 8];
#pragma unroll
        for (int i = 0; i < 4; i++)
#pragma unroll
            for (int j = 0; j < 4; j++) acc[i][j] = MFMA(af[i], bfr[j], acc[i][j]);
    }
#pragma unroll
    for (int i = 0; i < 4; i++) {
#pragma unroll
        for (int r = 0; r < 4; r++) {
            int row = m0 + mw + i * 16 + quad * 4 + r;
            float scale = 1.0f - qmask[row];
#pragma unroll
            for (int j = 0; j < 4; j++) {
                int col = n0 + nw + j * 16 + c;
                Cf[(size_t)row * 1024 + col] = acc[i][j][r] * scale;
            }
        }
    }
}

// ---------------- flash attention: R11 structure + single-barrier pipeline ----------------
// 1D grid 512, 512 thr, cohort perm {0,7,1,6,2,5,3,4}, pair-balanced. Per-chunk pipeline
// fused to ONE barrier: vmcnt(0) [own chunk-ci DMA done] -> lgkmcnt(0)+s_barrier [all waves'
// prior-buffer reads done AND all chunk-ci DMAs done] -> prefetch ci+1 -> compute ci.
// Sweep 1: S^T orientation (b64 P-stores, scalar lsum). Sweep 2: rebalanced column marginals.
__global__ __launch_bounds__(512) void attn_kernel(const u16* __restrict__ Qp, const u16* __restrict__ Kp,
                                                   const u16* __restrict__ Vt, u16* __restrict__ Pre,
                                                   float* __restrict__ marg) {
    __shared__ __align__(16) u16 Ks[2][64 * 64];
    __shared__ __align__(16) u16 Vs[2][64 * 64];
    __shared__ __align__(16) u16 plds[8][16 * 72];
    float* colbuf = (float*)&Vs[0][0];   // 4KB alias; live only in sweep 2
    float* wrbuf  = (float*)&plds[0][0]; // 128 floats alias; live only in sweep 2
    int tid = threadIdx.x;
    int bid = blockIdx.x;
    int k2 = bid >> 6;
    int m = (k2 & 1) ? (7 - (k2 >> 1)) : (k2 >> 1);  // cohort perm {0,7,1,6,2,5,3,4}
    int g = bid & 63;
    int h = g & 15, b = g >> 4;
    int bx = m;
    int nA = 16 - bx, nB = bx + 1;
    int w = tid >> 6, lane = tid & 63, quad = lane >> 4, c = lane & 15;

    int nq = (w < 4) ? nA : nB;
    int q0 = (w < 4) ? ((15 - bx) * 64 + w * 16) : (bx * 64 + (w - 4) * 16);

    const u16* qrow = Qp + (size_t)(b * 1024 + q0 + c) * 1024 + h * 64;
    bf16x8 aq0 = *(const bf16x8*)(qrow + quad * 8);
    bf16x8 aq1 = *(const bf16x8*)(qrow + 32 + quad * 8);

    const u16* kb = Kp + (size_t)b * 1024 * 1024 + h * 64;
    const u16* vb = Vt + (size_t)(b * 16 + h) * 64 * 1024;
    u16* pl = plds[w];

    int rowS = tid >> 3;
    int lu = (tid & 7) ^ (rowS & 7);
    int sw = c & 7;
    int su0 = (quad ^ sw) * 8;
    int su1 = ((quad ^ 4) ^ sw) * 8;
    u16* ldsK = &Ks[0][0] + w * 512;
    u16* ldsV = &Vs[0][0] + w * 512;

    f32x4 o[4];
#pragma unroll
    for (int i = 0; i < 4; i++) o[i] = zero4();
    float lsum = 0.f;
    int qg[4];
#pragma unroll
    for (int r = 0; r < 4; r++) qg[r] = q0 + quad * 4 + r;

    // ---------------- sweep 1: S^T -> exp -> P(LDS, b64 stores) -> PV ----------------
    gl_lds16(kb + (size_t)rowS * 1024 + lu * 8, ldsK);
    gl_lds16(vb + (size_t)rowS * 1024 + lu * 8, ldsV);
    for (int ci = 0; ci < nA; ci++) {
        int bf = ci & 1;
        asm volatile("s_waitcnt vmcnt(0)" ::: "memory");  // own chunk-ci DMA done
        barrier_nodrain();                                 // + all waves: prior reads done, DMAs done
        if (ci + 1 < nA) {
            gl_lds16(kb + (size_t)((ci + 1) * 64 + rowS) * 1024 + lu * 8, ldsK + (bf ^ 1) * 4096);
            gl_lds16(vb + (size_t)rowS * 1024 + (ci + 1) * 64 + lu * 8,  ldsV + (bf ^ 1) * 4096);
        }
        if (ci < nq) {
            const u16* Kb = &Ks[bf][0];
            const u16* Vb = &Vs[bf][0];
            f32x4 sT[4];
#pragma unroll
            for (int j = 0; j < 4; j++) {
                const u16* kr = Kb + (j * 16 + c) * 64;
                sT[j] = MFMA(*(const bf16x8*)(kr + su0), aq0, zero4());
                sT[j] = MFMA(*(const bf16x8*)(kr + su1), aq1, sT[j]);
            }
            if (ci < nq - 1) {
#pragma unroll
                for (int j = 0; j < 4; j++) {
                    u16 tmp[4];
#pragma unroll
                    for (int r = 0; r < 4; r++) {
                        float e = exp2f(sT[j][r]);
                        lsum += e;
                        tmp[r] = f2bf(e);
                    }
                    *(uint2*)&pl[c * 72 + j * 16 + quad * 4] = *(const uint2*)tmp;
                }
            } else {
                int qq = q0 + c;
#pragma unroll
                for (int j = 0; j < 4; j++) {
                    int tl = ci * 64 + j * 16 + quad * 4;
                    u16 tmp[4];
#pragma unroll
                    for (int r = 0; r < 4; r++) {
                        float e = (tl + r <= qq) ? exp2f(sT[j][r]) : 0.f;
                        lsum += e;
                        tmp[r] = f2bf(e);
                    }
                    *(uint2*)&pl[c * 72 + j * 16 + quad * 4] = *(const uint2*)tmp;
                }
            }
            asm volatile("s_waitcnt lgkmcnt(0)" ::: "memory");
            bf16x8 ap0 = *(const bf16x8*)&pl[c * 72 + quad * 8];
            bf16x8 ap1 = *(const bf16x8*)&pl[c * 72 + 32 + quad * 8];
#pragma unroll
            for (int vt = 0; vt < 4; vt++) {
                const u16* vr = Vb + (vt * 16 + c) * 64;
                o[vt] = MFMA(ap0, *(const bf16x8*)(vr + su0), o[vt]);
                o[vt] = MFMA(ap1, *(const bf16x8*)(vr + su1), o[vt]);
            }
        }
    }

    lsum += __shfl_xor(lsum, 16);
    lsum += __shfl_xor(lsum, 32);
    float invc = 1.0f / lsum;
    float invl[4];
#pragma unroll
    for (int r = 0; r < 4; r++) invl[r] = __shfl(invc, quad * 4 + r);
#pragma unroll
    for (int vt = 0; vt < 4; vt++)
#pragma unroll
        for (int r = 0; r < 4; r++) {
            size_t row = (size_t)(b * 1024 + q0 + quad * 4 + r);
            Pre[row * 1024 + h * 64 + vt * 16 + c] = f2bf(o[vt][r] * invl[r]);
        }

    // ---------------- sweep 2: column marginals sum_q att[q,t]*(q+1), rebalanced ----------------
    float wr[4];
#pragma unroll
    for (int r = 0; r < 4; r++) wr[r] = (float)(qg[r] + 1) * invl[r];

    bf16x8 aqH0 = aq0, aqH1 = aq1;
    int q0H = q0;
    if (w >= 4) {
        q0H = (15 - bx) * 64 + (w - 4) * 16;
        const u16* qrowH = Qp + (size_t)(b * 1024 + q0H + c) * 1024 + h * 64;
        aqH0 = *(const bf16x8*)(qrowH + quad * 8);
        aqH1 = *(const bf16x8*)(qrowH + 32 + quad * 8);
    }
    asm volatile("s_waitcnt vmcnt(0)" ::: "memory");  // drain Pre stores + aqH loads
    __syncthreads();                                  // plds/Vs reads done -> aliases safe
    if (c == 0) {
#pragma unroll
        for (int r = 0; r < 4; r++) wrbuf[w * 16 + quad * 4 + r] = wr[r];
    }
    gl_lds16(kb + (size_t)rowS * 1024 + lu * 8, ldsK);
    for (int i = tid; i < nA * 64; i += 512) colbuf[i] = 0.f;
    __syncthreads();                                  // colbuf + wrbuf visible
    float wrH[4];
    int qgH[4];
#pragma unroll
    for (int r = 0; r < 4; r++) {
        qgH[r] = q0H + quad * 4 + r;
        wrH[r] = (w < 4) ? wr[r] : wrbuf[(w - 4) * 16 + quad * 4 + r];
    }

    for (int ci = 0; ci < nA; ci++) {
        int bf = ci & 1;
        asm volatile("s_waitcnt vmcnt(0)" ::: "memory");  // own chunk-ci K DMA done
        barrier_nodrain();
        if (ci + 1 < nA) {
            gl_lds16(kb + (size_t)((ci + 1) * 64 + rowS) * 1024 + lu * 8, ldsK + (bf ^ 1) * 4096);
        }
        const u16* Kb = &Ks[bf][0];
        if (ci < nB) {
            f32x4 s[4];
#pragma unroll
            for (int j = 0; j < 4; j++) {
                const u16* kr = Kb + (j * 16 + c) * 64;
                s[j] = MFMA(aq0, *(const bf16x8*)(kr + su0), zero4());
                s[j] = MFMA(aq1, *(const bf16x8*)(kr + su1), s[j]);
            }
            bool diag = (w >= 4) && (ci == nB - 1);
            float a[4];
#pragma unroll
            for (int j = 0; j < 4; j++) {
                int t = ci * 64 + j * 16 + c;
                float aj = 0.f;
#pragma unroll
                for (int r = 0; r < 4; r++) {
                    float term = exp2f(s[j][r]) * wr[r];
                    aj += (!diag || t <= qg[r]) ? term : 0.f;
                }
                aj += __shfl_xor(aj, 16);
                aj += __shfl_xor(aj, 32);
                a[j] = aj;
            }
            float v = (quad == 0) ? a[0] : (quad == 1) ? a[1] : (quad == 2) ? a[2] : a[3];
            atomicAdd(&colbuf[ci * 64 + lane], v);
        } else {
            int jb = (w >= 4) ? 2 : 0;
            f32x4 s2[2];
#pragma unroll
            for (int jj = 0; jj < 2; jj++) {
                const u16* kr = Kb + ((jb + jj) * 16 + c) * 64;
                s2[jj] = MFMA(aqH0, *(const bf16x8*)(kr + su0), zero4());
                s2[jj] = MFMA(aqH1, *(const bf16x8*)(kr + su1), s2[jj]);
            }
            bool diag = (ci == nA - 1);
            float a2[2];
#pragma unroll
            for (int jj = 0; jj < 2; jj++) {
                int t = ci * 64 + (jb + jj) * 16 + c;
                float aj = 0.f;
#pragma unroll
                for (int r = 0; r < 4; r++) {
                    float term = exp2f(s2[jj][r]) * wrH[r];
                    aj += (!diag || t <= qgH[r]) ? term : 0.f;
                }
                aj += __shfl_xor(aj, 16);
                aj += __shfl_xor(aj, 32);
                a2[jj] = aj;
            }
            float v = (quad == 0) ? a2[0] : a2[1];
            if (quad < 2) atomicAdd(&colbuf[ci * 64 + (jb + quad) * 16 + c], v);
        }
    }
    __syncthreads();
    for (int t = tid; t < nA * 64; t += 512) atomicAdd(&marg[b * 1024 + t], colbuf[t]);
}

extern "C" void kernel_launch(void* const* d_in, const int* in_sizes, int n_in,
                              void* d_out, int out_size, void* d_ws, size_t ws_size,
                              hipStream_t stream) {
    const float* qinput  = (const float*)d_in[0];
    const float* kvinput = (const float*)d_in[1];
    const float* qmask   = (const float*)d_in[2];
    const float* wq = (const float*)d_in[5];
    const float* wk = (const float*)d_in[6];
    const float* wv = (const float*)d_in[7];
    const float* wo = (const float*)d_in[8];

    char* ws = (char*)d_ws;
    const size_t MB = 1024 * 1024;
    u16* Xq   = (u16*)(ws + 0);        // 8MB, reused as Pre after Q-proj consumed
    u16* Xkv  = (u16*)(ws + 8 * MB);   // 8MB
    u16* W3   = (u16*)(ws + 16 * MB);  // Wqt|Wkt|Wvt contiguous, 2MB each
    u16* Wot  = (u16*)(ws + 22 * MB);
    u16* Qp   = (u16*)(ws + 24 * MB);  // 8MB (pre-scaled by QSC)
    u16* Kp   = (u16*)(ws + 32 * MB);  // 8MB
    u16* Vt   = (u16*)(ws + 40 * MB);  // 8MB (B,H,V,T)
    float* marg = (float*)(ws + 48 * MB);  // 16KB
    u16* Pre = Xq;
    float* out = (float*)d_out;

    prep_kernel<<<9217, 256, 0, stream>>>(qinput, kvinput, Xq, Xkv, wq, wk, wv, wo, W3, Wot, marg);
    proj_kernel<<<512, 256, 0, stream>>>(Xq, Xkv, W3, Qp, Kp, Vt);

    attn_kernel<<<512, 512, 0, stream>>>(Qp, Kp, Vt, Pre, marg);  // Pre overwrites Xq
    gemmo_kernel<<<260, 256, 0, stream>>>(Pre, Wot, out, qmask, marg, out + (size_t)4 * 1024 * 1024);
}